// Round 6
// baseline (522.563 us; speedup 1.0000x reference)
//
#include <hip/hip_runtime.h>
#include <hip/hip_bf16.h>

// LinkClassifier: out[e] = relu(concat(h[s],h[t],ea,pooled[batch[s]]) @ W1 + b1) @ W2 + b2
// R10: algebraic split. Per-node precompute (dense GEMM):
//   P1'[v] = h[v]@W1a + pooled[batch[v]]@W1d + b1   (cols 0..127 of P12)
//   P2 [v] = h[v]@W1b                               (cols 128..255 of P12)
// stored f32 (no added rounding). Edge kernel: dense streamed ea@W1c (128-K MFMA,
// zero gathers on the MFMA path) + epilogue-only scalar f32 gathers of P12[s]/P12[t]
// feeding VALU adds -> gather latency fully decoupled from barriers/MFMA.
// 3.5x fewer FLOPs, 1KB/edge random reads (was 1.5KB). R9 path kept as ws fallback.

typedef __attribute__((ext_vector_type(8))) short bf16x8;
typedef __attribute__((ext_vector_type(4))) float f32x4;
typedef __attribute__((address_space(3))) char lds_char;
typedef __attribute__((address_space(1))) const void g_cvoid;

constexpr int kND = 256;
constexpr int kED = 128;
constexpr int kH  = 128;
constexpr int kB  = 2048;  // NUM_GRAPHS
constexpr int TM  = 128;   // edges per block
constexpr int kNF = 224;   // old-path W frag-sets

__device__ __forceinline__ void gl2lds16(const void* gsrc, lds_char* ldst) {
  __builtin_amdgcn_global_load_lds((g_cvoid*)gsrc,
                                   (__attribute__((address_space(3))) void*)ldst,
                                   16, 0, 0);
}

__device__ __forceinline__ ushort f2bf(float x) {
  union { float f; unsigned u; } c; c.f = x;
  unsigned u = c.u + 0x7FFFu + ((c.u >> 16) & 1u);
  return (ushort)(u >> 16);
}
__device__ __forceinline__ float bf2f(ushort x) {
  union { unsigned u; float f; } c; c.u = ((unsigned)x) << 16;
  return c.f;
}
__device__ __forceinline__ bool data_is_f32(const void* p) {
  const unsigned* u = (const unsigned*)p;
  int cnt = 0;
  #pragma unroll
  for (int i = 0; i < 64; ++i) {
    unsigned e = (u[i] >> 7) & 0xFFu;
    cnt += (e >= 90u && e <= 140u) ? 1 : 0;
  }
  return cnt < 40;
}
__device__ __forceinline__ bool idx_is_64(const int* __restrict__ p) {
  return ((p[1] | p[3] | p[5] | p[7]) == 0) && ((p[0] | p[2] | p[4] | p[6]) != 0);
}
__device__ __forceinline__ float loadf(const void* p, int i, bool isf32) {
  return isf32 ? ((const float*)p)[i] : bf2f(((const ushort*)p)[i]);
}

// ---------------- pooling: per-graph mean; optionally converts h->hbf (old path) ----------------
__global__ __launch_bounds__(256) void pool_kernel(
    const void* __restrict__ hv, ushort* __restrict__ hbf, int preconv,
    const int* __restrict__ batch, const int* __restrict__ ei, int N,
    ushort* __restrict__ pooled) {
  const bool isf32 = data_is_f32(hv);
  const bool is64 = idx_is_64(ei);
  const int b = blockIdx.x, tid = threadIdx.x;
  __shared__ int bounds[2];
  __shared__ float sred[8][kND];
  if (tid < 2) {
    int target = b + tid;
    int lo = 0, hi = N;
    while (lo < hi) {
      int mid = (lo + hi) >> 1;
      int v = is64 ? batch[2 * mid] : batch[mid];
      if (v < target) lo = mid + 1; else hi = mid;
    }
    bounds[tid] = lo;
  }
  __syncthreads();
  const int lo = bounds[0], hi = bounds[1];
  const int dg = tid & 31;
  const int rstr = tid >> 5;
  float a[8];
  #pragma unroll
  for (int j = 0; j < 8; ++j) a[j] = 0.f;

  if (!isf32) {
    const ushort* base = (const ushort*)hv + dg * 8;
    int r = lo + rstr;
    for (; r + 8 < hi; r += 16) {
      union { uint4 v; ushort us[8]; } u0, u1;
      u0.v = *(const uint4*)(base + (size_t)r * kND);
      u1.v = *(const uint4*)(base + (size_t)(r + 8) * kND);
      #pragma unroll
      for (int j = 0; j < 8; ++j) a[j] += bf2f(u0.us[j]);
      #pragma unroll
      for (int j = 0; j < 8; ++j) a[j] += bf2f(u1.us[j]);
    }
    for (; r < hi; r += 8) {
      union { uint4 v; ushort us[8]; } u0;
      u0.v = *(const uint4*)(base + (size_t)r * kND);
      #pragma unroll
      for (int j = 0; j < 8; ++j) a[j] += bf2f(u0.us[j]);
    }
  } else if (preconv) {
    const float* base = (const float*)hv + dg * 8;
    ushort* wb = hbf + dg * 8;
    for (int r = lo + rstr; r < hi; r += 8) {
      float4 f0 = *(const float4*)(base + (size_t)r * kND);
      float4 f1 = *(const float4*)(base + (size_t)r * kND + 4);
      union { ushort us[8]; uint4 v; } cv;
      cv.us[0] = f2bf(f0.x); cv.us[1] = f2bf(f0.y);
      cv.us[2] = f2bf(f0.z); cv.us[3] = f2bf(f0.w);
      cv.us[4] = f2bf(f1.x); cv.us[5] = f2bf(f1.y);
      cv.us[6] = f2bf(f1.z); cv.us[7] = f2bf(f1.w);
      *(uint4*)(wb + (size_t)r * kND) = cv.v;
      a[0] += f0.x; a[1] += f0.y; a[2] += f0.z; a[3] += f0.w;
      a[4] += f1.x; a[5] += f1.y; a[6] += f1.z; a[7] += f1.w;
    }
  } else {
    const float* base = (const float*)hv + dg * 8;
    for (int r = lo + rstr; r < hi; r += 8) {
      float4 f0 = *(const float4*)(base + (size_t)r * kND);
      float4 f1 = *(const float4*)(base + (size_t)r * kND + 4);
      a[0] += f0.x; a[1] += f0.y; a[2] += f0.z; a[3] += f0.w;
      a[4] += f1.x; a[5] += f1.y; a[6] += f1.z; a[7] += f1.w;
    }
  }
  #pragma unroll
  for (int j = 0; j < 8; ++j) sred[rstr][dg * 8 + j] = a[j];
  __syncthreads();
  int cnt = hi - lo; if (cnt < 1) cnt = 1;
  float inv = 1.f / (float)cnt;
  float s = 0.f;
  #pragma unroll
  for (int st = 0; st < 8; ++st) s += sred[st][tid];
  pooled[(size_t)b * kND + tid] = f2bf(s * inv);
}

// ---------------- Pg[2048][128] = pooled @ W1d + b1 (f32) ----------------
__global__ __launch_bounds__(256) void pg_kernel(
    const ushort* __restrict__ pooled, const void* __restrict__ W1v,
    const void* __restrict__ b1v, float* __restrict__ Pg) {
  const bool w32 = data_is_f32(W1v);
  const bool b32 = data_is_f32(b1v);
  const int tid = threadIdx.x;
  const int g = blockIdx.x * 2 + (tid >> 7);
  const int n = tid & 127;
  float acc = loadf(b1v, n, b32);
  const ushort* pr = pooled + (size_t)g * kND;
  #pragma unroll 8
  for (int k = 0; k < 256; ++k)
    acc += bf2f(pr[k]) * loadf(W1v, (640 + k) * kH + n, w32);
  Pg[(size_t)g * 128 + n] = acc;
}

// ---------------- new Wfrag builder: node (128 sets) + edge (32 sets) ----------------
// B-frag: lane l holds B[n][k] for n = base + ni*16 + (l&15), k = ksg*32 + (l>>4)*8 + j
// node: f = ksg*16 + nq*4 + ni (ksg 0..7, nq 0..3): n_l = nq*64+ni*16+l15 (0..255);
//       W1 row = n_l<128 ? k : 256+k ; col = n_l&127
// edge: fe = ksg*8 + nhi*4 + ni (ksg 0..3): n = nhi*64+ni*16+l15; W1 row = 512+k; col = n
__global__ __launch_bounds__(256) void build_wfrag2(
    const void* __restrict__ W1v, ushort* __restrict__ WfragN) {
  const bool isf32 = data_is_f32(W1v);
  int idx = blockIdx.x * 256 + threadIdx.x;
  if (idx >= 160 * 64) return;
  int l = idx & 63, f = idx >> 6;
  int row0, col;
  int kj = (l >> 4) * 8;  // k sub-offset
  if (f < 128) {
    int ni = f & 3, nq = (f >> 2) & 3, ksg = f >> 4;
    int n_l = nq * 64 + ni * 16 + (l & 15);
    int k0 = ksg * 32 + kj;
    row0 = (n_l < 128) ? k0 : (256 + k0);
    col = n_l & 127;
  } else {
    int fe = f - 128;
    int ni = fe & 3, nhi = (fe >> 2) & 1, ksg = fe >> 3;
    int n = nhi * 64 + ni * 16 + (l & 15);
    row0 = 512 + ksg * 32 + kj;
    col = n;
  }
  union { ushort us[8]; uint4 v; } cv;
  #pragma unroll
  for (int j = 0; j < 8; ++j)
    cv.us[j] = f2bf(loadf(W1v, (row0 + j) * kH + col, isf32));
  *(uint4*)(WfragN + (size_t)f * 512 + l * 8) = cv.v;
}

// ---------------- node_kernel: P12[v][0:128]=h@W1a+Pg[batch[v]] ; [128:256]=h@W1b ----------------
__global__ __launch_bounds__(512, 4) void node_kernel(
    const void* __restrict__ hv, const int* __restrict__ batch,
    const int* __restrict__ ei, int N, const ushort* __restrict__ WfragN,
    const float* __restrict__ Pg, float* __restrict__ P12) {
  __shared__ __align__(16) char Xh[128 * 256];  // 32KB bf16 tile (one K-half)
  __shared__ int gs[128];
  const bool hf32 = data_is_f32(hv);
  const bool is64 = idx_is_64(ei);
  const int tid = threadIdx.x;
  const int v0 = blockIdx.x * 128;

  if (tid < 128) {
    int v = v0 + tid; if (v >= N) v = N - 1;
    gs[tid] = is64 ? batch[2 * v] : batch[v];
  }

  const int wave = tid >> 6, lane = tid & 63;
  const int l15 = lane & 15, quad = lane >> 4;
  const int mh = (wave & 1) * 64;   // row half
  const int cq = wave >> 1;         // 64-col quarter (0..3)
  const ushort* wl = WfragN + lane * 8;
  const int r = tid >> 2, q = tid & 3;
  int vr = v0 + r; if (vr >= N) vr = N - 1;

  f32x4 acc[4][4];
  #pragma unroll
  for (int i = 0; i < 4; ++i)
    #pragma unroll
    for (int j = 0; j < 4; ++j)
      acc[i][j] = (f32x4){0.f, 0.f, 0.f, 0.f};

  for (int p = 0; p < 2; ++p) {
    // ---- stage K-half p: thread (r,q) covers dims p*128+q*32..+31 ----
    if (hf32) {
      const float4* src = (const float4*)hv + (size_t)vr * 64 + p * 32 + q * 8;
      #pragma unroll
      for (int j = 0; j < 4; ++j) {
        float4 f0 = src[2 * j], f1 = src[2 * j + 1];
        union { ushort us[8]; uint4 v; } cv;
        cv.us[0] = f2bf(f0.x); cv.us[1] = f2bf(f0.y);
        cv.us[2] = f2bf(f0.z); cv.us[3] = f2bf(f0.w);
        cv.us[4] = f2bf(f1.x); cv.us[5] = f2bf(f1.y);
        cv.us[6] = f2bf(f1.z); cv.us[7] = f2bf(f1.w);
        *(uint4*)&Xh[r * 256 + ((q * 64 + j * 16) ^ ((r & 7) << 4))] = cv.v;
      }
    } else {
      const uint4* src = (const uint4*)hv + (size_t)vr * 32 + p * 16 + q * 4;
      #pragma unroll
      for (int j = 0; j < 4; ++j)
        *(uint4*)&Xh[r * 256 + ((q * 64 + j * 16) ^ ((r & 7) << 4))] = src[j];
    }
    __syncthreads();
    // ---- GEMM K-half p ----
    #pragma unroll
    for (int ks = 0; ks < 4; ++ks) {
      bf16x8 bq[4];
      #pragma unroll
      for (int ni = 0; ni < 4; ++ni)
        bq[ni] = *(const bf16x8*)(wl +
            (size_t)(((p * 4 + ks) * 16 + cq * 4 + ni)) * 512);
      bf16x8 af[4];
      #pragma unroll
      for (int mi = 0; mi < 4; ++mi) {
        int row = mh + mi * 16 + l15;
        int cb = ks * 64 + quad * 16;
        af[mi] = *(const bf16x8*)&Xh[row * 256 + (cb ^ ((row & 7) << 4))];
      }
      #pragma unroll
      for (int mi = 0; mi < 4; ++mi)
        #pragma unroll
        for (int ni = 0; ni < 4; ++ni)
          acc[mi][ni] = __builtin_amdgcn_mfma_f32_16x16x32_bf16(
              af[mi], bq[ni], acc[mi][ni], 0, 0, 0);
    }
    __syncthreads();
  }

  // ---- epilogue: +Pg for cols<128, scatter f32 to P12 ----
  #pragma unroll
  for (int mi = 0; mi < 4; ++mi)
    #pragma unroll
    for (int ni = 0; ni < 4; ++ni) {
      int col = cq * 64 + ni * 16 + l15;
      #pragma unroll
      for (int j = 0; j < 4; ++j) {
        int row = mh + mi * 16 + quad * 4 + j;
        int v = v0 + row;
        if (v < N) {
          float val = acc[mi][ni][j];
          if (col < 128) val += Pg[(size_t)gs[row] * 128 + col];
          P12[(size_t)v * 256 + col] = val;
        }
      }
    }
}

// ---------------- edge_kernel_new: dense ea@W1c + epilogue P12 gathers ----------------
__global__ __launch_bounds__(512, 4) void edge_kernel_new(
    const void* __restrict__ hv, const int* __restrict__ ei,
    const void* __restrict__ eav, const ushort* __restrict__ WfragE,
    const float* __restrict__ P12, const void* __restrict__ W2v,
    const void* __restrict__ b2v, void* __restrict__ outv, int E) {
  __shared__ __align__(16) char Xe[128 * 256];  // 32KB bf16 ea tile
  __shared__ int rs[TM], rt[TM];
  __shared__ float outacc[TM];
  __shared__ float w2s[kH];
  const bool isf32 = data_is_f32(hv);     // output dtype convention
  const bool ea32 = data_is_f32(eav);
  const bool w232 = data_is_f32(W2v);
  const bool is64 = idx_is_64(ei);
  const int tid = threadIdx.x;
  const int e0 = blockIdx.x * TM;

  if (tid < TM) {
    int e = e0 + tid; if (e >= E) e = E - 1;
    rs[tid] = is64 ? ei[2 * e] : ei[e];
    rt[tid] = is64 ? ei[2 * (E + e)] : ei[E + e];
    w2s[tid] = loadf(W2v, tid, w232);
    outacc[tid] = 0.f;
  }

  // ---- stage ea tile: thread (r,q) covers dims q*32..+31 of edge e0+r ----
  const int r = tid >> 2, q = tid & 3;
  int er = e0 + r; if (er >= E) er = E - 1;
  if (ea32) {
    const float4* src = (const float4*)eav + (size_t)er * 32 + q * 8;
    #pragma unroll
    for (int j = 0; j < 4; ++j) {
      float4 f0 = src[2 * j], f1 = src[2 * j + 1];
      union { ushort us[8]; uint4 v; } cv;
      cv.us[0] = f2bf(f0.x); cv.us[1] = f2bf(f0.y);
      cv.us[2] = f2bf(f0.z); cv.us[3] = f2bf(f0.w);
      cv.us[4] = f2bf(f1.x); cv.us[5] = f2bf(f1.y);
      cv.us[6] = f2bf(f1.z); cv.us[7] = f2bf(f1.w);
      *(uint4*)&Xe[r * 256 + ((q * 64 + j * 16) ^ ((r & 7) << 4))] = cv.v;
    }
  } else {
    const uint4* src = (const uint4*)eav + (size_t)er * 16 + q * 4;
    #pragma unroll
    for (int j = 0; j < 4; ++j)
      *(uint4*)&Xe[r * 256 + ((q * 64 + j * 16) ^ ((r & 7) << 4))] = src[j];
  }
  __syncthreads();

  const int wave = tid >> 6, lane = tid & 63;
  const int l15 = lane & 15, quad = lane >> 4;
  const int mh = (wave & 1) * 64;
  const int nq = wave >> 1;
  const int nhi = nq >> 1;
  const int nlo = (nq & 1) * 2;
  const ushort* wl = WfragE + lane * 8;

  f32x4 acc[4][2];
  #pragma unroll
  for (int i = 0; i < 4; ++i)
    #pragma unroll
    for (int j = 0; j < 2; ++j)
      acc[i][j] = (f32x4){0.f, 0.f, 0.f, 0.f};

  // ---- GEMM: eaG = ea @ W1c (K=128) ----
  #pragma unroll
  for (int ks = 0; ks < 4; ++ks) {
    bf16x8 bq[2];
    #pragma unroll
    for (int ni = 0; ni < 2; ++ni)
      bq[ni] = *(const bf16x8*)(wl +
          (size_t)(ks * 8 + nhi * 4 + (nlo + ni)) * 512);
    bf16x8 af[4];
    #pragma unroll
    for (int mi = 0; mi < 4; ++mi) {
      int row = mh + mi * 16 + l15;
      int cb = ks * 64 + quad * 16;
      af[mi] = *(const bf16x8*)&Xe[row * 256 + (cb ^ ((row & 7) << 4))];
    }
    #pragma unroll
    for (int mi = 0; mi < 4; ++mi)
      #pragma unroll
      for (int ni = 0; ni < 2; ++ni)
        acc[mi][ni] = __builtin_amdgcn_mfma_f32_16x16x32_bf16(
            af[mi], bq[ni], acc[mi][ni], 0, 0, 0);
  }

  // ---- epilogue: + P1'[s] + P2[t] (scalar f32 gathers), relu, dot w2, reduce ----
  #pragma unroll
  for (int mi = 0; mi < 4; ++mi) {
    float ps[4] = {0.f, 0.f, 0.f, 0.f};
    #pragma unroll
    for (int ni = 0; ni < 2; ++ni) {
      int col = nhi * 64 + (nlo + ni) * 16 + l15;
      float w2v = w2s[col];
      #pragma unroll
      for (int j = 0; j < 4; ++j) {
        int row = mh + mi * 16 + quad * 4 + j;
        float p1 = P12[(size_t)rs[row] * 256 + col];
        float p2 = P12[(size_t)rt[row] * 256 + 128 + col];
        float v = acc[mi][ni][j] + p1 + p2;
        ps[j] += (v > 0.f ? v : 0.f) * w2v;
      }
    }
    #pragma unroll
    for (int off = 1; off < 16; off <<= 1)
      #pragma unroll
      for (int j = 0; j < 4; ++j)
        ps[j] += __shfl_xor(ps[j], off, 64);
    if (l15 == 0)
      #pragma unroll
      for (int j = 0; j < 4; ++j)
        atomicAdd(&outacc[mh + mi * 16 + quad * 4 + j], ps[j]);
  }
  __syncthreads();
  if (tid < TM) {
    int e = e0 + tid;
    if (e < E) {
      float a = outacc[tid] + loadf(b2v, 0, data_is_f32(b2v));
      if (isf32) ((float*)outv)[e] = a;
      else       ((ushort*)outv)[e] = f2bf(a);
    }
  }
}

// ================= OLD (R9) fallback path =================
__global__ __launch_bounds__(256) void build_wfrag(
    const void* __restrict__ W1v, ushort* __restrict__ Wfrag) {
  const bool isf32 = data_is_f32(W1v);
  int idx = blockIdx.x * 256 + threadIdx.x;
  if (idx >= kNF * 64) return;
  int l = idx & 63, f = idx >> 6;
  int ni = f & 3, nhi = (f >> 2) & 1, ksg = f >> 3;
  int tile = ksg >> 2;
  int basek = (tile == 0) ? 512 : ((tile < 5) ? (tile - 1) * 128 : tile * 128);
  int n = nhi * 64 + ni * 16 + (l & 15);
  int k0 = basek + (ksg & 3) * 32 + (l >> 4) * 8;
  union { ushort us[8]; uint4 v; } cv;
  #pragma unroll
  for (int j = 0; j < 8; ++j)
    cv.us[j] = f2bf(loadf(W1v, (k0 + j) * kH + n, isf32));
  *(uint4*)(Wfrag + (size_t)f * 512 + l * 8) = cv.v;
}

template<bool HB, bool EA32> struct TD;
template<> struct TD<true, true> {
  static constexpr int NT = 8;
  static constexpr int ty[8]  = {0,0,1,1,2,2,3,3};
  static constexpr int sub[8] = {0,1,0,1,0,1,0,1};
  static constexpr int ksc[8] = {2,2,4,4,4,4,4,4};
  static constexpr int kg0[8] = {0,2,4,8,12,16,20,24};
  static constexpr bool tf32[8] = {1,1,0,0,0,0,0,0};
};
template<> struct TD<true, false> {
  static constexpr int NT = 7;
  static constexpr int ty[7]  = {0,1,1,2,2,3,3};
  static constexpr int sub[7] = {0,0,1,0,1,0,1};
  static constexpr int ksc[7] = {4,4,4,4,4,4,4};
  static constexpr int kg0[7] = {0,4,8,12,16,20,24};
  static constexpr bool tf32[7] = {0,0,0,0,0,0,0};
};
template<> struct TD<false, true> {
  static constexpr int NT = 12;
  static constexpr int ty[12]  = {0,0,1,1,1,1,2,2,2,2,3,3};
  static constexpr int sub[12] = {0,1,0,1,2,3,0,1,2,3,0,1};
  static constexpr int ksc[12] = {2,2,2,2,2,2,2,2,2,2,4,4};
  static constexpr int kg0[12] = {0,2,4,6,8,10,12,14,16,18,20,24};
  static constexpr bool tf32[12] = {1,1,1,1,1,1,1,1,1,1,0,0};
};
template<> struct TD<false, false> {
  static constexpr int NT = 11;
  static constexpr int ty[11]  = {0,1,1,1,1,2,2,2,2,3,3};
  static constexpr int sub[11] = {0,0,1,2,3,0,1,2,3,0,1};
  static constexpr int ksc[11] = {4,2,2,2,2,2,2,2,2,4,4};
  static constexpr int kg0[11] = {0,4,6,8,10,12,14,16,18,20,24};
  static constexpr bool tf32[11] = {0,1,1,1,1,1,1,1,1,0,0};
};

template<bool HB, bool EA32>
__device__ __forceinline__ void edge_core(
    const char* __restrict__ hsrc, const char* __restrict__ easrc,
    const ushort* __restrict__ pooled, const ushort* __restrict__ Wfrag,
    const char* XlB, lds_char* Xl3, const int* rs, const int* rt, const int* rg,
    int e0, int E, int wave, int lane, f32x4 (&acc)[4][2]) {
  using T = TD<HB, EA32>;
  const int l15 = lane & 15, quad = lane >> 4;
  const int mh = (wave & 1) * 64;
  const int nq = wave >> 1;
  const int nhi = nq >> 1;
  const int nlo = (nq & 1) * 2;
  const ushort* wl = Wfrag + (size_t)nhi * 2048 + lane * 8;
  const int cx0 = (lane & 15) * 16;
  const int rlane = lane >> 4;

  auto src_addr = [&](int t, int row) -> const char* {
    int cx = cx0 ^ ((row & 7) << 4);
    int ty = T::ty[t], sub = T::sub[t];
    if (ty == 0) {
      int e = e0 + row; if (e >= E) e = E - 1;
      return easrc + (size_t)e * (EA32 ? 512 : 256) + sub * 256 + cx;
    }
    if (ty == 1) return hsrc + (size_t)rs[row] * (HB ? 512 : 1024) + sub * 256 + cx;
    if (ty == 2) return hsrc + (size_t)rt[row] * (HB ? 512 : 1024) + sub * 256 + cx;
    return (const char*)pooled + (size_t)rg[row] * 512 + sub * 256 + cx;
  };
  auto stage = [&](int t) {
    lds_char* dst = Xl3 + (t & 1) * 32768;
    #pragma unroll
    for (int i = 0; i < 4; ++i) {
      int row = wave * 16 + i * 4 + rlane;
      gl2lds16(src_addr(t, row), dst + (wave * 16 + i * 4) * 256);
    }
  };

  stage(0);
  __syncthreads();

  #pragma unroll
  for (int t = 0; t < T::NT; ++t) {
    bf16x8 bq[8];
    #pragma unroll
    for (int ks = 0; ks < T::ksc[t]; ++ks)
      #pragma unroll
      for (int ni = 0; ni < 2; ++ni)
        bq[ks * 2 + ni] =
            *(const bf16x8*)(wl + (size_t)(T::kg0[t] + ks) * 4096 + (nlo + ni) * 512);
    __builtin_amdgcn_sched_barrier(0);
    if (t + 1 < T::NT) stage(t + 1);

    const char* xb = XlB + (t & 1) * 32768;
    #pragma unroll
    for (int ks = 0; ks < T::ksc[t]; ++ks) {
      bf16x8 af[4];
      #pragma unroll
      for (int mi = 0; mi < 4; ++mi) {
        int row = mh + mi * 16 + l15;
        int sz = (row & 7) << 4;
        const char* rb = xb + row * 256;
        if (T::tf32[t]) {
          int cb = ks * 128 + quad * 32;
          float4 f0 = *(const float4*)(rb + (cb ^ sz));
          float4 f1 = *(const float4*)(rb + ((cb + 16) ^ sz));
          union { ushort us[8]; bf16x8 v; } cv;
          cv.us[0] = f2bf(f0.x); cv.us[1] = f2bf(f0.y);
          cv.us[2] = f2bf(f0.z); cv.us[3] = f2bf(f0.w);
          cv.us[4] = f2bf(f1.x); cv.us[5] = f2bf(f1.y);
          cv.us[6] = f2bf(f1.z); cv.us[7] = f2bf(f1.w);
          af[mi] = cv.v;
        } else {
          int cb = ks * 64 + quad * 16;
          af[mi] = *(const bf16x8*)(rb + (cb ^ sz));
        }
      }
      #pragma unroll
      for (int mi = 0; mi < 4; ++mi)
        #pragma unroll
        for (int ni = 0; ni < 2; ++ni)
          acc[mi][ni] = __builtin_amdgcn_mfma_f32_16x16x32_bf16(
              af[mi], bq[ks * 2 + ni], acc[mi][ni], 0, 0, 0);
    }
    __syncthreads();
  }
}

__global__ __launch_bounds__(512, 4) void edge_kernel_old(
    const void* __restrict__ hv, const ushort* __restrict__ hbf, int preconv,
    const int* __restrict__ ei, const void* __restrict__ eav,
    const int* __restrict__ batch, const ushort* __restrict__ pooled,
    const ushort* __restrict__ Wfrag, const void* __restrict__ b1v,
    const void* __restrict__ W2v, const void* __restrict__ b2v,
    void* __restrict__ outv, int E) {
  __shared__ __align__(16) char XlB[2 * 32768];
  __shared__ int rs[TM], rt[TM], rg[TM];
  __shared__ float outacc[TM];
  __shared__ float b1s[kH], w2s[kH];
  lds_char* Xl3 = (lds_char*)XlB;

  const int tid = threadIdx.x;
  const int e0 = blockIdx.x * TM;
  const bool isf32 = data_is_f32(hv);
  const bool is64 = idx_is_64(ei);

  if (tid < TM) {
    int e = e0 + tid; if (e >= E) e = E - 1;
    int s = is64 ? ei[2 * e] : ei[e];
    int t = is64 ? ei[2 * (E + e)] : ei[E + e];
    rs[tid] = s;
    rt[tid] = t;
    rg[tid] = is64 ? batch[2 * s] : batch[s];
    w2s[tid] = loadf(W2v, tid, isf32);
    b1s[tid] = loadf(b1v, tid, isf32);
    outacc[tid] = 0.f;
  }
  __syncthreads();

  const int wave = tid >> 6, lane = tid & 63;
  const int l15 = lane & 15, quad = lane >> 4;
  const int mh = (wave & 1) * 64;
  const int nq = wave >> 1;
  const int nhi = nq >> 1;
  const int nlo = (nq & 1) * 2;

  f32x4 acc[4][2];
  #pragma unroll
  for (int i = 0; i < 4; ++i)
    #pragma unroll
    for (int j = 0; j < 2; ++j)
      acc[i][j] = (f32x4){0.f, 0.f, 0.f, 0.f};

  const bool hb = !isf32 || preconv;
  const char* hsrc = !isf32 ? (const char*)hv
                            : (preconv ? (const char*)hbf : (const char*)hv);
  const bool ea32 = data_is_f32(eav);

  if (hb) {
    if (ea32) edge_core<true, true >((const char*)hsrc, (const char*)eav, pooled,
                                     Wfrag, XlB, Xl3, rs, rt, rg, e0, E, wave, lane, acc);
    else      edge_core<true, false>((const char*)hsrc, (const char*)eav, pooled,
                                     Wfrag, XlB, Xl3, rs, rt, rg, e0, E, wave, lane, acc);
  } else {
    if (ea32) edge_core<false, true >((const char*)hsrc, (const char*)eav, pooled,
                                      Wfrag, XlB, Xl3, rs, rt, rg, e0, E, wave, lane, acc);
    else      edge_core<false, false>((const char*)hsrc, (const char*)eav, pooled,
                                      Wfrag, XlB, Xl3, rs, rt, rg, e0, E, wave, lane, acc);
  }

  float w2v[2], b1r[2];
  #pragma unroll
  for (int ni = 0; ni < 2; ++ni) {
    int n = nhi * 64 + (nlo + ni) * 16 + l15;
    w2v[ni] = w2s[n];
    b1r[ni] = b1s[n];
  }
  #pragma unroll
  for (int mi = 0; mi < 4; ++mi) {
    float ps[4] = {0.f, 0.f, 0.f, 0.f};
    #pragma unroll
    for (int ni = 0; ni < 2; ++ni)
      #pragma unroll
      for (int j = 0; j < 4; ++j) {
        float v = acc[mi][ni][j] + b1r[ni];
        ps[j] += (v > 0.f ? v : 0.f) * w2v[ni];
      }
    #pragma unroll
    for (int off = 1; off < 16; off <<= 1)
      #pragma unroll
      for (int j = 0; j < 4; ++j)
        ps[j] += __shfl_xor(ps[j], off, 64);
    if (l15 == 0)
      #pragma unroll
      for (int j = 0; j < 4; ++j)
        atomicAdd(&outacc[mh + mi * 16 + quad * 4 + j], ps[j]);
  }
  __syncthreads();
  if (tid < TM) {
    int e = e0 + tid;
    if (e < E) {
      float a = outacc[tid] + loadf(b2v, 0, isf32);
      if (isf32) ((float*)outv)[e] = a;
      else       ((ushort*)outv)[e] = f2bf(a);
    }
  }
}

extern "C" void kernel_launch(void* const* d_in, const int* in_sizes, int n_in,
                              void* d_out, int out_size, void* d_ws, size_t ws_size,
                              hipStream_t stream) {
  const void* h   = d_in[0];
  const int*  ei  = (const int*)d_in[1];
  const void* ea  = d_in[2];
  const int*  bat = (const int*)d_in[3];
  const void* W1  = d_in[4];
  const void* b1  = d_in[5];
  const void* W2  = d_in[6];
  const void* b2  = d_in[7];

  const int N = in_sizes[3];
  const int E = in_sizes[1] / 2;

  // new ws layout: pooled bf16 [2048][256] | Pg f32 [2048][128] |
  //                WfragN+E bf16 [160*512] | P12 f32 [N][256]
  ushort* pooled = (ushort*)d_ws;
  float*  Pg     = (float*)(pooled + (size_t)kB * kND);
  ushort* WfragN = (ushort*)(Pg + (size_t)kB * 128);
  ushort* WfragE = WfragN + (size_t)128 * 512;
  float*  P12    = (float*)(WfragE + (size_t)32 * 512);
  const size_t need_new = (size_t)kB * kND * 2 + (size_t)kB * 128 * 4 +
                          (size_t)160 * 512 * 2 + (size_t)N * 256 * 4;

  if (ws_size >= need_new) {
    pool_kernel<<<kB, 256, 0, stream>>>(h, nullptr, 0, bat, ei, N, pooled);
    build_wfrag2<<<40, 256, 0, stream>>>(W1, WfragN);
    pg_kernel<<<kB / 2, 256, 0, stream>>>(pooled, W1, b1, Pg);
    node_kernel<<<(N + 127) / 128, 512, 0, stream>>>(h, bat, ei, N, WfragN, Pg, P12);
    edge_kernel_new<<<(E + TM - 1) / TM, 512, 0, stream>>>(
        h, ei, ea, WfragE, P12, W2, b2, d_out, E);
  } else {
    // old R9 path: pooled | Wfrag(224) | hbf
    ushort* Wfrag = pooled + (size_t)kB * kND;
    ushort* hbf   = Wfrag + (size_t)kNF * 512;
    const size_t need_old =
        ((size_t)kB * kND + (size_t)kNF * 512 + (size_t)N * kND) * sizeof(ushort);
    const int preconv = (ws_size >= need_old) ? 1 : 0;
    pool_kernel<<<kB, 256, 0, stream>>>(h, hbf, preconv, bat, ei, N, pooled);
    build_wfrag<<<(kNF * 64 + 255) / 256, 256, 0, stream>>>(W1, Wfrag);
    edge_kernel_old<<<(E + TM - 1) / TM, 512, 0, stream>>>(
        h, hbf, preconv, ei, ea, bat, pooled, Wfrag, b1, W2, b2, d_out, E);
  }
}